// Round 18
// baseline (140.002 us; speedup 1.0000x reference)
//
#include <hip/hip_runtime.h>
#include <hip/hip_bf16.h>
#include <math.h>

typedef unsigned short u16;
typedef __attribute__((ext_vector_type(8))) short short8;
typedef __attribute__((ext_vector_type(4))) float f32x4;
typedef __attribute__((ext_vector_type(4))) unsigned short u16x4;
typedef __attribute__((ext_vector_type(4))) unsigned int u32x4;

#define DEVI static __device__ __forceinline__

DEVI u16 f2bf(float f){
  union { float f; unsigned u; } c; c.f = f;
  unsigned r = (c.u + 0x7fffu + ((c.u >> 16) & 1u)) >> 16;
  return (u16)r;
}

DEVI unsigned cvtpk(float lo, float hi){
  unsigned r;
  asm("v_cvt_pk_bf16_f32 %0, %1, %2" : "=v"(r) : "v"(lo), "v"(hi));
  return r;
}

DEVI void async16(const void* g, void* l){
  __builtin_amdgcn_global_load_lds(
    (const __attribute__((address_space(1))) unsigned int*)g,
    (__attribute__((address_space(3))) unsigned int*)l, 16, 0, 0);
}

// counted-vmcnt barrier: wait until <=N VMEM instr outstanding, then barrier.
#define WAIT_BAR(N) asm volatile("s_waitcnt vmcnt(" #N ") lgkmcnt(0)\n\ts_barrier" ::: "memory")

// GEMM staging tiles (4 slots/row of 16B): physical chunk for (row r, group g)
#define ACHUNK(r, g) (((r) << 2) | (((g) + ((r) >> 1)) & 3))
// attn K tiles: 128 rows x 8 slots, full-r rotation (conflict-free b128 reads)
#define KCH(r, g) (((r) << 3) | (((g) + (r)) & 7))
// attn V tiles: 64 rows x 16 slots, full-d rotation
#define VCH(d, g) (((d) << 4) | (((g) + (d)) & 15))

// ---------------- fused fp32 -> bf16 conversion (x, Wqkv, Wproj) ----------------
__global__ __launch_bounds__(256) void cvt3(const float4* __restrict__ x,
                                            const float4* __restrict__ wq,
                                            const float4* __restrict__ wp,
                                            u16* __restrict__ xb,
                                            u16* __restrict__ wqb,
                                            u16* __restrict__ wpb){
  int i = blockIdx.x * 256 + threadIdx.x;
  const float4* s; u16* d; int off;
  if (i < 1048576)      { s = x;  d = xb;  off = i; }
  else if (i < 2621440) { s = wq; d = wqb; off = i - 1048576; }
  else                  { s = wp; d = wpb; off = i - 2621440; }
  float4 v = s[off];
  u16x4 o;
  o.x = f2bf(v.x); o.y = f2bf(v.y); o.z = f2bf(v.z); o.w = f2bf(v.w);
  *(u16x4*)(d + (size_t)off * 4) = o;
}

// ---------------- qkv GEMM (128x128, 4 waves, paired tiles, stage interval) ------
// Epilogue: q pre-scaled by log2(e) so attn softmax can use raw exp2.
__global__ __launch_bounds__(256) void gemm_qkv(const u16* __restrict__ A,
                                                const u16* __restrict__ B,
                                                const float* __restrict__ qg,
                                                const float* __restrict__ at_,
                                                u16* __restrict__ qb,
                                                u16* __restrict__ kb,
                                                u16* __restrict__ vT){
  const int K = 2048;
  __shared__ __align__(16) u16 As[4][4096];
  __shared__ __align__(16) u16 Bs[4][4096];
  const int bid = blockIdx.x;
  const int xcd = bid & 7, pos = bid >> 3;          // pos in [0,48)
  const int xm = xcd & 1, xn = xcd >> 1;            // XCD grid 2(m) x 4(n)
  const int mIdx = xm * 8 + (pos & 7);
  const int nIdx = xn * 6 + (pos >> 3);
  const int tid  = threadIdx.x;
  const int lane = tid & 63, wid = tid >> 6;
  const int wr = wid >> 1, wc = wid & 1;
  const int fr = lane & 15, fg = lane >> 4;
  const int mBase = mIdx * 128, nBase = nIdx * 128;

  f32x4 acc[4][4];
  for (int m = 0; m < 4; ++m)
    for (int n = 0; n < 4; ++n)
      for (int e = 0; e < 4; ++e) acc[m][n][e] = 0.f;

  const int c0 = tid, c1 = tid + 256;
  const int p0 = c0 >> 2, q0 = ((c0 & 3) - (p0 >> 1)) & 3;
  const int p1 = c1 >> 2, q1 = ((c1 & 3) - (p1 >> 1)) & 3;
  const u16* Ab = A + (size_t)mBase * K;
  const u16* Bb = B + (size_t)nBase * K;

  int ca[4], cb[4];
#pragma unroll
  for (int m = 0; m < 4; ++m){ const int r = wr * 64 + m * 16 + fr; ca[m] = ACHUNK(r, fg); }
#pragma unroll
  for (int n = 0; n < 4; ++n){ const int r = wc * 64 + n * 16 + fr; cb[n] = ACHUNK(r, fg); }

#define STAGE_QKV(kt) do {                                                 \
    const int b_ = (kt) & 3;                                               \
    const int kO_ = (kt) * 32;                                             \
    async16(Ab + (size_t)p0 * K + kO_ + q0 * 8, As[b_] + c0 * 8);          \
    async16(Ab + (size_t)p1 * K + kO_ + q1 * 8, As[b_] + c1 * 8);          \
    async16(Bb + (size_t)p0 * K + kO_ + q0 * 8, Bs[b_] + c0 * 8);          \
    async16(Bb + (size_t)p1 * K + kO_ + q1 * 8, Bs[b_] + c1 * 8);          \
  } while (0)

  STAGE_QKV(0); STAGE_QKV(1); STAGE_QKV(2); STAGE_QKV(3);

#pragma unroll 1
  for (int p = 0; p < 32; ++p){
    if (p < 31) WAIT_BAR(8);
    else        WAIT_BAR(0);
#pragma unroll
    for (int kk = 0; kk < 2; ++kk){
      const int cur = (2 * p + kk) & 3;
      short8 a[4], b[4];
#pragma unroll
      for (int m = 0; m < 4; ++m)
        a[m] = *(const short8*)(As[cur] + ca[m] * 8);
#pragma unroll
      for (int n = 0; n < 4; ++n)
        b[n] = *(const short8*)(Bs[cur] + cb[n] * 8);
      __builtin_amdgcn_s_setprio(1);
#pragma unroll
      for (int m = 0; m < 4; ++m)
#pragma unroll
        for (int n = 0; n < 4; ++n)
          acc[m][n] = __builtin_amdgcn_mfma_f32_16x16x32_bf16(a[m], b[n], acc[m][n], 0, 0, 0);
      __builtin_amdgcn_s_setprio(0);
    }
    __builtin_amdgcn_s_barrier();
    if (p < 30){ STAGE_QKV(2 * p + 4); STAGE_QKV(2 * p + 5); }
  }
#undef STAGE_QKV

  // fused epilogue. col64-block: 0..31 = q heads, 32..39 = k heads, 40..47 = v heads
  const int nb64 = nIdx * 2 + wc;
  if (nb64 < 40){
    const bool isq = nb64 < 32;
    const int h = isq ? nb64 : (nb64 - 32);
    // q additionally scaled by log2(e) so softmax uses exp2 directly
    const float gsc = isq ? (qg[h] * at_[h] * 0.125f * 1.44269504f) : 1.0f;
    u16* dst = isq ? qb : kb;
#pragma unroll
    for (int m = 0; m < 4; ++m)
#pragma unroll
      for (int e = 0; e < 4; ++e){
        const int t = mBase + wr * 64 + m * 16 + fg * 4 + e;
        const float ft = (float)t;
#pragma unroll
        for (int np = 0; np < 2; ++np){
          const int d = np * 16 + fr;
          const float ang = ft * ((float)d * 0.03125f);
          float sn, cs; sincosf(ang, &sn, &cs);
          const float x1 = acc[m][np][e], x2 = acc[m][np + 2][e];
          u16* base = dst + ((size_t)h * 2048 + t) * 64 + d;
          base[0]  = f2bf((x1 * cs - x2 * sn) * gsc);
          base[32] = f2bf((x1 * sn + x2 * cs) * gsc);
        }
      }
  } else {
    const int h = nb64 - 40;
#pragma unroll
    for (int m = 0; m < 4; ++m){
      const int t0 = mBase + wr * 64 + m * 16 + fg * 4;
#pragma unroll
      for (int n = 0; n < 4; ++n){
        const int d = n * 16 + fr;
        u16x4 pk;
#pragma unroll
        for (int e = 0; e < 4; ++e) pk[e] = f2bf(acc[m][n][e]);
        *(u16x4*)(vT + ((size_t)h * 64 + d) * 2048 + t0) = pk;
      }
    }
  }
}

// ---------------- causal flash attention v8 (KVBLK=128, exp2 softmax) ------------
// Per-head blocks (grid 16x32, 256 thr). One softmax round per 128 k (half the
// per-k overhead of v7). q pre-scaled by log2e -> raw exp2f. 2-deep dbuf, 64KB.
__global__ __launch_bounds__(256) void attn_fwd(const u16* __restrict__ qb,
                                                const u16* __restrict__ kb,
                                                const u16* __restrict__ vT,
                                                u16* __restrict__ yb){
  const int bx = blockIdx.x, h = blockIdx.y;
  const int hk = h >> 2;
  const int tid = threadIdx.x;
  const int lane = tid & 63, wid = tid >> 6;
  const int fr = lane & 15, fg = lane >> 4;

  __shared__ __align__(16) u16 Ks[2][8192];   // [128 k][64 d], KCH chunks
  __shared__ __align__(16) u16 Vs[2][8192];   // [64 d][128 k], VCH chunks

  const u16* kbh = kb + (size_t)hk * 2048 * 64;
  const u16* vTh = vT + (size_t)hk * 64 * 2048;

  // staging indices: 1024 chunks per operand, 4 per thread (c = tid + j*256)
  int kq_[4], kpr[4], vd_[4], vg_[4];
#pragma unroll
  for (int j = 0; j < 4; ++j){
    const int c = tid + j * 256;
    const int kp = c >> 3;  kq_[j] = ((c & 7) - kp) & 7;
    kpr[j] = ((kp >> 5) << 5) | (((kp >> 2) & 3) << 3) | (((kp >> 4) & 1) << 2) | (kp & 3);
    vd_[j] = c >> 4;        vg_[j] = ((c & 15) - vd_[j]) & 15;
  }

  // fragment physical chunks (constant per thread)
  int ck[2][8], cv[4][4];
#pragma unroll
  for (int kcd = 0; kcd < 2; ++kcd)
#pragma unroll
    for (int cf = 0; cf < 8; ++cf)
      ck[kcd][cf] = KCH(cf * 16 + fr, kcd * 4 + fg);
#pragma unroll
  for (int kc = 0; kc < 4; ++kc)
#pragma unroll
    for (int df = 0; df < 4; ++df)
      cv[kc][df] = VCH(df * 16 + fr, kc * 4 + fg);

// stage K/V tile kt (128 k rows) into buffer b: 8 async16 per thread
#define STAGE_KV(kt, b) do {                                                  \
    const size_t kO_ = (size_t)(kt) * 128;                                    \
    _Pragma("unroll")                                                         \
    for (int j = 0; j < 4; ++j){                                              \
      const int c_ = tid + j * 256;                                           \
      async16(kbh + (kO_ + kpr[j]) * 64 + kq_[j] * 8, Ks[b] + (size_t)c_ * 8);\
      async16(vTh + (size_t)vd_[j] * 2048 + kO_ + vg_[j] * 8,                 \
              Vs[b] + (size_t)c_ * 8);                                        \
    }                                                                         \
  } while (0)

#pragma unroll 1
  for (int seg = 0; seg < 2; ++seg){
    const int qt = seg ? (31 - bx) : bx;
    const int nt = (qt + 2) >> 1;            // 128-wide k tiles
    const int qrow0 = qt * 64 + wid * 16;
    const int q = qrow0 + fr;                // this lane's q-row

    short8 qf[2];
    {
      const u16* qp = qb + ((size_t)h * 2048 + q) * 64 + fg * 8;
      qf[0] = *(const short8*)(qp);
      qf[1] = *(const short8*)(qp + 32);
    }

    float mrow = -1e30f, lrow = 0.f;
    f32x4 o[4];
    for (int df = 0; df < 4; ++df)
      for (int e = 0; e < 4; ++e) o[df][e] = 0.f;

    STAGE_KV(0, 0);

#pragma unroll 1
    for (int kt = 0; kt < nt; ++kt){
      const int cur = kt & 1;
      __syncthreads();                        // drains stage(kt), protects reuse
      if (kt + 1 < nt) STAGE_KV(kt + 1, cur ^ 1);
      const u16* Kb = Ks[cur];
      const u16* Vb = Vs[cur];

      // S'^T : s[cf][r] = S'[q][kt*128 + (cf>>1)*32 + fg*8 + (cf&1)*4 + r]
      f32x4 s[8];
      __builtin_amdgcn_s_setprio(1);
#pragma unroll
      for (int cf = 0; cf < 8; ++cf){
        for (int e = 0; e < 4; ++e) s[cf][e] = 0.f;
#pragma unroll
        for (int kcd = 0; kcd < 2; ++kcd){
          short8 kf = *(const short8*)(Kb + ck[kcd][cf] * 8);
          s[cf] = __builtin_amdgcn_mfma_f32_16x16x32_bf16(kf, qf[kcd], s[cf], 0, 0, 0);
        }
      }
      __builtin_amdgcn_s_setprio(0);

      // causal mask
      if (kt * 128 + 127 > qrow0){
#pragma unroll
        for (int cf = 0; cf < 8; ++cf){
          const int kb0 = kt * 128 + (cf >> 1) * 32 + (cf & 1) * 4 + fg * 8;
#pragma unroll
          for (int r = 0; r < 4; ++r)
            if (kb0 + r > q) s[cf][r] = -1e30f;
        }
      }

      // lane-local softmax (base-2 domain) with defer-max (THR = 8*log2e)
      float mt = -1e30f;
#pragma unroll
      for (int cf = 0; cf < 8; ++cf)
        mt = fmaxf(mt, fmaxf(fmaxf(s[cf][0], s[cf][1]), fmaxf(s[cf][2], s[cf][3])));
      mt = fmaxf(mt, __shfl_xor(mt, 16));
      mt = fmaxf(mt, __shfl_xor(mt, 32));
      if (!__all(mt <= mrow + 11.5416f)){
        const float mn = fmaxf(mrow, mt);
        const float al = exp2f(mrow - mn);
        lrow *= al;
#pragma unroll
        for (int df = 0; df < 4; ++df)
#pragma unroll
          for (int e = 0; e < 4; ++e) o[df][e] *= al;
        mrow = mn;
      }
      float rs = 0.f;
#pragma unroll
      for (int cf = 0; cf < 8; ++cf){
#pragma unroll
        for (int r = 0; r < 4; ++r){
          s[cf][r] = exp2f(s[cf][r] - mrow);
          rs += s[cf][r];
        }
      }
      rs += __shfl_xor(rs, 16);
      rs += __shfl_xor(rs, 32);
      lrow += rs;

      // pack P -> 4 PV B-fragments fully in-register
      union { u32x4 u; short8 s8; } pb[4];
#pragma unroll
      for (int kc = 0; kc < 4; ++kc){
        pb[kc].u[0] = cvtpk(s[kc * 2][0],     s[kc * 2][1]);
        pb[kc].u[1] = cvtpk(s[kc * 2][2],     s[kc * 2][3]);
        pb[kc].u[2] = cvtpk(s[kc * 2 + 1][0], s[kc * 2 + 1][1]);
        pb[kc].u[3] = cvtpk(s[kc * 2 + 1][2], s[kc * 2 + 1][3]);
      }

      __builtin_amdgcn_s_setprio(1);
#pragma unroll
      for (int df = 0; df < 4; ++df){
#pragma unroll
        for (int kc = 0; kc < 4; ++kc){
          short8 v = *(const short8*)(Vb + cv[kc][df] * 8);
          o[df] = __builtin_amdgcn_mfma_f32_16x16x32_bf16(v, pb[kc].s8, o[df], 0, 0, 0);
        }
      }
      __builtin_amdgcn_s_setprio(0);
    }
    __syncthreads();   // protect LDS before next segment's prologue stage

    const float inv = 1.f / lrow;
#pragma unroll
    for (int df = 0; df < 4; ++df){
      u16x4 pk;
#pragma unroll
      for (int e = 0; e < 4; ++e) pk[e] = f2bf(o[df][e] * inv);
      *(u16x4*)(yb + (size_t)q * 2048 + h * 64 + df * 16 + fg * 4) = pk;
    }
  }
#undef STAGE_KV
}

// ---------------- proj GEMM (128x128, 4 waves, paired tiles, stage interval) -----
__global__ __launch_bounds__(256) void gemm_bt(const u16* __restrict__ A,
                                               const u16* __restrict__ B,
                                               float* __restrict__ C,
                                               int M, int N, int K){
  __shared__ __align__(16) u16 As[4][4096];
  __shared__ __align__(16) u16 Bs[4][4096];
  const int bid = blockIdx.x;
  const int xcd = bid & 7, pos = bid >> 3;          // pos in [0,32)
  const int xm = xcd & 1, xn = xcd >> 1;            // XCD grid 2(m) x 4(n)
  const int mIdx = xm * 8 + (pos & 7);
  const int nIdx = xn * 4 + (pos >> 3);
  const int tid  = threadIdx.x;
  const int lane = tid & 63, wid = tid >> 6;
  const int wr = wid >> 1, wc = wid & 1;
  const int fr = lane & 15, fg = lane >> 4;
  const int mBase = mIdx * 128, nBase = nIdx * 128;

  f32x4 acc[4][4];
  for (int m = 0; m < 4; ++m)
    for (int n = 0; n < 4; ++n)
      for (int e = 0; e < 4; ++e) acc[m][n][e] = 0.f;

  const int c0 = tid, c1 = tid + 256;
  const int p0 = c0 >> 2, q0 = ((c0 & 3) - (p0 >> 1)) & 3;
  const int p1 = c1 >> 2, q1 = ((c1 & 3) - (p1 >> 1)) & 3;
  const u16* Ab = A + (size_t)mBase * K;
  const u16* Bb = B + (size_t)nBase * K;

  int ca[4], cb[4];
#pragma unroll
  for (int m = 0; m < 4; ++m){ const int r = wr * 64 + m * 16 + fr; ca[m] = ACHUNK(r, fg); }
#pragma unroll
  for (int n = 0; n < 4; ++n){ const int r = wc * 64 + n * 16 + fr; cb[n] = ACHUNK(r, fg); }

#define STAGE_BT(kt) do {                                                  \
    const int b_ = (kt) & 3;                                               \
    const int kO_ = (kt) * 32;                                             \
    async16(Ab + (size_t)p0 * K + kO_ + q0 * 8, As[b_] + c0 * 8);          \
    async16(Ab + (size_t)p1 * K + kO_ + q1 * 8, As[b_] + c1 * 8);          \
    async16(Bb + (size_t)p0 * K + kO_ + q0 * 8, Bs[b_] + c0 * 8);          \
    async16(Bb + (size_t)p1 * K + kO_ + q1 * 8, Bs[b_] + c1 * 8);          \
  } while (0)

  STAGE_BT(0); STAGE_BT(1); STAGE_BT(2); STAGE_BT(3);

  const int np = K >> 6;   // pairs
#pragma unroll 1
  for (int p = 0; p < np; ++p){
    if (p < np - 1) WAIT_BAR(8);
    else            WAIT_BAR(0);
#pragma unroll
    for (int kk = 0; kk < 2; ++kk){
      const int cur = (2 * p + kk) & 3;
      short8 a[4], b[4];
#pragma unroll
      for (int m = 0; m < 4; ++m)
        a[m] = *(const short8*)(As[cur] + ca[m] * 8);
#pragma unroll
      for (int n = 0; n < 4; ++n)
        b[n] = *(const short8*)(Bs[cur] + cb[n] * 8);
      __builtin_amdgcn_s_setprio(1);
#pragma unroll
      for (int m = 0; m < 4; ++m)
#pragma unroll
        for (int n = 0; n < 4; ++n)
          acc[m][n] = __builtin_amdgcn_mfma_f32_16x16x32_bf16(a[m], b[n], acc[m][n], 0, 0, 0);
      __builtin_amdgcn_s_setprio(0);
    }
    __builtin_amdgcn_s_barrier();
    if (p < np - 2){ STAGE_BT(2 * p + 4); STAGE_BT(2 * p + 5); }
  }
#undef STAGE_BT

  for (int m = 0; m < 4; ++m){
    const int row = mBase + wr * 64 + m * 16 + fg * 4;
    for (int n = 0; n < 4; ++n){
      const int col = nBase + wc * 64 + n * 16 + fr;
      for (int e = 0; e < 4; ++e)
        C[(size_t)(row + e) * N + col] = acc[m][n][e];
    }
  }
}

extern "C" void kernel_launch(void* const* d_in, const int* in_sizes, int n_in,
                              void* d_out, int out_size, void* d_ws, size_t ws_size,
                              hipStream_t stream){
  (void)in_sizes; (void)n_in; (void)out_size; (void)ws_size;
  const float* x     = (const float*)d_in[0];
  const float* Wqkv  = (const float*)d_in[1];
  const float* Wproj = (const float*)d_in[2];
  const float* qg    = (const float*)d_in[3];
  const float* at    = (const float*)d_in[4];
  float* out = (float*)d_out;

  u16* xb     = (u16*)d_ws;              // 2048*2048
  u16* wqkvb  = xb + 4194304;            // 3072*2048
  u16* wprojb = wqkvb + 6291456;         // 2048*2048
  u16* qbuf   = wprojb + 4194304;        // 32*2048*64
  u16* kbuf   = qbuf + 4194304;          // 8*2048*64
  u16* vTb    = kbuf + 1048576;          // 8*64*2048
  u16* ybuf   = vTb + 1048576;           // 2048*2048

  cvt3<<<14336, 256, 0, stream>>>((const float4*)x, (const float4*)Wqkv,
                                  (const float4*)Wproj, xb, wqkvb, wprojb);
  gemm_qkv<<<384, 256, 0, stream>>>(xb, wqkvb, qg, at, qbuf, kbuf, vTb);
  attn_fwd<<<dim3(16, 32), 256, 0, stream>>>(qbuf, kbuf, vTb, ybuf);
  gemm_bt<<<256, 256, 0, stream>>>(ybuf, wprojb, out, 2048, 2048, 2048);
}